// Round 1
// baseline (2469.943 us; speedup 1.0000x reference)
//
#include <hip/hip_runtime.h>
#include <hip/hip_bf16.h>

// ---------------------------------------------------------------------------
// Nystromformer attention, fp32 baseline.
// B=4, L=4096, D=1024, H=16, HD=64, NL=64, SEG=64, INV_ITERS=6
// ---------------------------------------------------------------------------

static constexpr int Bn  = 4;
static constexpr int Ln  = 4096;
static constexpr int Dn  = 1024;
static constexpr int Hn  = 16;
static constexpr int HDn = 64;
static constexpr int NLn = 64;
static constexpr int SEGn = 64;
static constexpr int BHn = Bn * Hn;     // 64
static constexpr int Mn  = Bn * Ln;     // 16384
#define NEG_BIG (-100000.0f)

// workspace offsets (in floats)
static constexpr size_t OFF_K   = 0;                        // 16777216 floats
static constexpr size_t OFF_Q   = 16777216;
static constexpr size_t OFF_V   = 33554432;
static constexpr size_t OFF_QLM = 50331648;                 // 262144 each below
static constexpr size_t OFF_KLM = OFF_QLM + 262144;
static constexpr size_t OFF_S2  = OFF_KLM + 262144;
static constexpr size_t OFF_Z   = OFF_S2  + 262144;
static constexpr size_t OFF_S3V = OFF_Z   + 262144;
static constexpr size_t OFF_W   = OFF_S3V + 262144;
static constexpr size_t OFF_GM  = OFF_W   + 262144;         // 2 ints
static constexpr size_t OFF_ATTN = OFF_K;                   // alias (Kt dead by then)

// ---------------------------------------------------------------------------
// K1: kqv = x @ w_kqv^T  (M=16384, N=3072, K=1024), scatter to Kt/Qt/Vt
// 128x128 tile, BK=8, 256 threads, 8x8 micro-tile (split 4+4 to avoid LDS
// 4-way conflicts on ds_read_b128).
// ---------------------------------------------------------------------------
__global__ __launch_bounds__(256) void k_kqv_gemm(
    const float* __restrict__ x, const float* __restrict__ w,
    const float* __restrict__ mask,
    float* __restrict__ Kt, float* __restrict__ Qt, float* __restrict__ Vt)
{
    __shared__ float As[8][132];
    __shared__ float Bs[8][132];
    const int tid = threadIdx.x;
    const int bm = blockIdx.x;          // 0..127
    const int bn = blockIdx.y;          // 0..23
    const int lrow = tid >> 1;          // 0..127
    const int lk4  = (tid & 1) << 2;    // 0 or 4
    const float* aP = x + (size_t)(bm * 128 + lrow) * Dn + lk4;
    const float* bP = w + (size_t)(bn * 128 + lrow) * Dn + lk4;
    const int tx = tid & 15, ty = tid >> 4;
    const int i0 = ty << 2, i1 = 64 + (ty << 2);
    const int j0 = tx << 2, j1 = 64 + (tx << 2);
    float acc[8][8] = {};
    float4 av = *(const float4*)aP;
    float4 bv = *(const float4*)bP;
    for (int kt = 0; kt < 128; ++kt) {
        __syncthreads();
        As[lk4 + 0][lrow] = av.x; As[lk4 + 1][lrow] = av.y;
        As[lk4 + 2][lrow] = av.z; As[lk4 + 3][lrow] = av.w;
        Bs[lk4 + 0][lrow] = bv.x; Bs[lk4 + 1][lrow] = bv.y;
        Bs[lk4 + 2][lrow] = bv.z; Bs[lk4 + 3][lrow] = bv.w;
        __syncthreads();
        if (kt < 127) {
            av = *(const float4*)(aP + (size_t)(kt + 1) * 8);
            bv = *(const float4*)(bP + (size_t)(kt + 1) * 8);
        }
        #pragma unroll
        for (int kk = 0; kk < 8; ++kk) {
            float ar[8], br[8];
            *(float4*)&ar[0] = *(const float4*)&As[kk][i0];
            *(float4*)&ar[4] = *(const float4*)&As[kk][i1];
            *(float4*)&br[0] = *(const float4*)&Bs[kk][j0];
            *(float4*)&br[4] = *(const float4*)&Bs[kk][j1];
            #pragma unroll
            for (int i = 0; i < 8; ++i)
                #pragma unroll
                for (int j = 0; j < 8; ++j)
                    acc[i][j] = fmaf(ar[i], br[j], acc[i][j]);
        }
    }
    #pragma unroll
    for (int i = 0; i < 8; ++i) {
        const int gm = bm * 128 + (i < 4 ? i0 + i : i1 + i - 4);
        const int b = gm >> 12, l = gm & (Ln - 1);
        const float mk = mask[b * Ln + l];
        #pragma unroll
        for (int jg = 0; jg < 2; ++jg) {
            const int gnb = bn * 128 + (jg ? j1 : j0);
            const int part = gnb >> 10, c = gnb & 1023;
            const int h = c >> 6, d = c & 63;
            const size_t idx = ((size_t)(b * Hn + h) * Ln + l) * HDn + d;
            float4 v;
            v.x = acc[i][jg * 4 + 0] * mk;
            v.y = acc[i][jg * 4 + 1] * mk;
            v.z = acc[i][jg * 4 + 2] * mk;
            v.w = acc[i][jg * 4 + 3] * mk;
            if (part == 0) {
                *(float4*)&Kt[idx] = v;
            } else if (part == 1) {
                v.x *= 0.125f; v.y *= 0.125f; v.z *= 0.125f; v.w *= 0.125f;
                *(float4*)&Qt[idx] = v;
            } else {
                *(float4*)&Vt[idx] = v;
            }
        }
    }
}

// ---------------------------------------------------------------------------
// K2: landmark means. grid = BH*NL blocks, 64 threads (d).
// ---------------------------------------------------------------------------
__global__ __launch_bounds__(64) void k_landmarks(
    const float* __restrict__ Kt, const float* __restrict__ Qt,
    const float* __restrict__ mask,
    float* __restrict__ klm, float* __restrict__ qlm)
{
    const int blk = blockIdx.x;           // bh*64 + m
    const int m = blk & 63, bh = blk >> 6, b = bh >> 4;
    const int d = threadIdx.x;
    float mv = mask[b * Ln + m * SEGn + d];
    #pragma unroll
    for (int off = 32; off; off >>= 1) mv += __shfl_down(mv, off);
    const float denom = __shfl(mv, 0) + 1e-8f;
    const float* kp = Kt + ((size_t)bh * Ln + m * SEGn) * HDn + d;
    const float* qp = Qt + ((size_t)bh * Ln + m * SEGn) * HDn + d;
    float sk = 0.f, sq = 0.f;
    for (int j = 0; j < SEGn; ++j) {
        sk += kp[(size_t)j * HDn];
        sq += qp[(size_t)j * HDn];
    }
    klm[((size_t)bh * NLn + m) * HDn + d] = sk / denom;
    qlm[((size_t)bh * NLn + m) * HDn + d] = sq / denom;
}

// ---------------------------------------------------------------------------
// K3: s2 = softmax(q_lm @ k_lm^T) (no mask: mask_lm==1 always) + global maxes
// of abs row-sums / col-sums for pinv init. grid=BH, 64 threads (row each).
// ---------------------------------------------------------------------------
__global__ __launch_bounds__(64) void k_s2(
    const float* __restrict__ qlm, const float* __restrict__ klm,
    float* __restrict__ s2, int* __restrict__ gmax)
{
    const int bh = blockIdx.x;
    __shared__ float ql[64][65];
    __shared__ float kl[64][65];
    __shared__ float sr[64][65];
    const int t = threadIdx.x;
    for (int idx = t; idx < 4096; idx += 64) {
        ql[idx >> 6][idx & 63] = qlm[(size_t)bh * 4096 + idx];
        kl[idx >> 6][idx & 63] = klm[(size_t)bh * 4096 + idx];
    }
    __syncthreads();
    float mx = -1e30f;
    for (int mp = 0; mp < 64; ++mp) {
        float s = 0.f;
        #pragma unroll 8
        for (int d2 = 0; d2 < 64; ++d2) s = fmaf(ql[t][d2], kl[mp][d2], s);
        sr[t][mp] = s;
        mx = fmaxf(mx, s);
    }
    float sum = 0.f;
    for (int mp = 0; mp < 64; ++mp) {
        const float e = expf(sr[t][mp] - mx);
        sr[t][mp] = e;
        sum += e;
    }
    const float inv = 1.f / sum;
    float rs = 0.f;
    for (int mp = 0; mp < 64; ++mp) {
        const float v = sr[t][mp] * inv;
        sr[t][mp] = v;
        s2[(size_t)bh * 4096 + t * 64 + mp] = v;
        rs += fabsf(v);
    }
    __syncthreads();
    float cs = 0.f;
    for (int mm = 0; mm < 64; ++mm) cs += fabsf(sr[mm][t]);
    float rmax = rs, cmax = cs;
    #pragma unroll
    for (int off = 32; off; off >>= 1) {
        rmax = fmaxf(rmax, __shfl_down(rmax, off));
        cmax = fmaxf(cmax, __shfl_down(cmax, off));
    }
    if (t == 0) {
        atomicMax(&gmax[0], __float_as_int(rmax));  // max over rows of |row|-sum
        atomicMax(&gmax[1], __float_as_int(cmax));  // max over cols of |col|-sum
    }
}

// ---------------------------------------------------------------------------
// 64x64 matmul helper: C = scl * A @ (SUB ? dg*I - B : B).
// Output write is barrier-separated from reads, so C may alias A or B.
// A may be a global pointer (L1-cached) or LDS.
// ---------------------------------------------------------------------------
template<int SUB>
__device__ __forceinline__ void mm64g(
    float* C, int ldc, const float* Ag, int lda,
    const float* Bm, int ldb, float dg, float scl)
{
    const int tid = threadIdx.x;
    const int tx = tid & 15, ty = tid >> 4;
    const int i0 = ty << 2, j0 = tx << 2;
    float acc[4][4] = {};
    for (int k = 0; k < 64; ++k) {
        float a[4], bb[4];
        #pragma unroll
        for (int i = 0; i < 4; ++i) a[i] = Ag[(size_t)(i0 + i) * lda + k];
        #pragma unroll
        for (int j = 0; j < 4; ++j) {
            float v = Bm[(size_t)k * ldb + j0 + j];
            if (SUB) v = ((k == j0 + j) ? dg : 0.0f) - v;
            bb[j] = v;
        }
        #pragma unroll
        for (int i = 0; i < 4; ++i)
            #pragma unroll
            for (int j = 0; j < 4; ++j) acc[i][j] = fmaf(a[i], bb[j], acc[i][j]);
    }
    __syncthreads();
    #pragma unroll
    for (int i = 0; i < 4; ++i)
        #pragma unroll
        for (int j = 0; j < 4; ++j) C[(size_t)(i0 + i) * ldc + j0 + j] = scl * acc[i][j];
    __syncthreads();
}

// ---------------------------------------------------------------------------
// K4: Moore-Penrose pinv of s2, 6 Newton-Schulz iterations. grid=BH, 256 thr.
// X stays in global (L1-hot, 16KB/block); Z/XZ/T in LDS (<64KB total).
// ---------------------------------------------------------------------------
__global__ __launch_bounds__(256) void k_pinv(
    const float* __restrict__ s2, const int* __restrict__ gmax,
    float* __restrict__ zout)
{
    __shared__ float Zb[64][65];
    __shared__ float XZ[64][65];
    __shared__ float Tb[64][64];
    const int bh = blockIdx.x;
    const int tid = threadIdx.x;
    const float* X = s2 + (size_t)bh * 4096;
    const float scale = 1.0f / (__int_as_float(gmax[0]) * __int_as_float(gmax[1]));
    for (int idx = tid; idx < 4096; idx += 256) {
        const int i = idx >> 6, j = idx & 63;
        Zb[i][j] = X[j * 64 + i] * scale;   // Z = X^T / (maxcol*maxrow)
    }
    __syncthreads();
    for (int it = 0; it < 6; ++it) {
        mm64g<0>(&XZ[0][0], 65, X, 64, &Zb[0][0], 65, 0.f, 1.f);       // XZ = X@Z
        mm64g<1>(&Tb[0][0], 64, &XZ[0][0], 65, &XZ[0][0], 65, 7.f, 1.f);  // T = XZ@(7I-XZ)
        mm64g<1>(&Tb[0][0], 64, &XZ[0][0], 65, &Tb[0][0], 64, 15.f, 1.f); // T = XZ@(15I-T)
        mm64g<1>(&Zb[0][0], 65, &Zb[0][0], 65, &Tb[0][0], 64, 13.f, 0.25f); // Z = .25*Z@(13I-T)
    }
    for (int idx = tid; idx < 4096; idx += 256)
        zout[(size_t)bh * 4096 + idx] = Zb[idx >> 6][idx & 63];
}

// ---------------------------------------------------------------------------
// K5: s3v = softmax_rows(q_lm @ K^T + maskterm) @ V, online softmax over L.
// grid=BH, 256 threads, acc 4x4/thread (64x64 output).
// ---------------------------------------------------------------------------
__global__ __launch_bounds__(256) void k_s3v(
    const float* __restrict__ qlm, const float* __restrict__ Kt,
    const float* __restrict__ Vt, const float* __restrict__ mask,
    float* __restrict__ s3v)
{
    __shared__ float Ql[64][65];
    __shared__ float Ks[64][65];
    __shared__ float Vs[64][64];
    __shared__ float S[64][65];
    __shared__ float rowmax[64], rowsum[64], fac[64], mrow[64];
    const int bh = blockIdx.x;
    const int b = bh >> 4;
    const int tid = threadIdx.x;
    const int tx = tid & 15, ty = tid >> 4;
    const int i0 = ty << 2, j0 = tx << 2;
    for (int idx = tid; idx < 4096; idx += 256)
        Ql[idx >> 6][idx & 63] = qlm[(size_t)bh * 4096 + idx];
    if (tid < 64) { rowmax[tid] = -1e30f; rowsum[tid] = 0.f; }
    float acc[4][4] = {};
    for (int t0 = 0; t0 < Ln; t0 += 64) {
        __syncthreads();
        for (int idx = tid; idx < 4096; idx += 256) {
            const int r = idx >> 6, c2 = idx & 63;
            Ks[r][c2] = Kt[((size_t)bh * Ln + t0 + r) * HDn + c2];
            Vs[r][c2] = Vt[((size_t)bh * Ln + t0 + r) * HDn + c2];
        }
        if (tid < 64) mrow[tid] = mask[b * Ln + t0 + tid];
        __syncthreads();
        float sacc[4][4] = {};
        for (int k = 0; k < 64; ++k) {
            float a[4], bb4[4];
            #pragma unroll
            for (int i = 0; i < 4; ++i) a[i] = Ql[i0 + i][k];
            #pragma unroll
            for (int j = 0; j < 4; ++j) bb4[j] = Ks[j0 + j][k];
            #pragma unroll
            for (int i = 0; i < 4; ++i)
                #pragma unroll
                for (int j = 0; j < 4; ++j) sacc[i][j] = fmaf(a[i], bb4[j], sacc[i][j]);
        }
        #pragma unroll
        for (int i = 0; i < 4; ++i)
            #pragma unroll
            for (int j = 0; j < 4; ++j)
                S[i0 + i][j0 + j] = sacc[i][j] + (1.f - mrow[j0 + j]) * NEG_BIG;
        __syncthreads();
        if (tid < 64) {
            const int m = tid;
            float mx = -1e30f;
            for (int j = 0; j < 64; ++j) mx = fmaxf(mx, S[m][j]);
            const float nm = fmaxf(rowmax[m], mx);
            const float f = expf(rowmax[m] - nm);
            float ps = 0.f;
            for (int j = 0; j < 64; ++j) {
                const float e = expf(S[m][j] - nm);
                S[m][j] = e;
                ps += e;
            }
            rowsum[m] = rowsum[m] * f + ps;
            rowmax[m] = nm;
            fac[m] = f;
        }
        __syncthreads();
        #pragma unroll
        for (int i = 0; i < 4; ++i) {
            const float f = fac[i0 + i];
            #pragma unroll
            for (int j = 0; j < 4; ++j) acc[i][j] *= f;
        }
        for (int k = 0; k < 64; ++k) {
            float a[4], bb4[4];
            #pragma unroll
            for (int i = 0; i < 4; ++i) a[i] = S[i0 + i][k];
            #pragma unroll
            for (int j = 0; j < 4; ++j) bb4[j] = Vs[k][j0 + j];
            #pragma unroll
            for (int i = 0; i < 4; ++i)
                #pragma unroll
                for (int j = 0; j < 4; ++j) acc[i][j] = fmaf(a[i], bb4[j], acc[i][j]);
        }
    }
    #pragma unroll
    for (int i = 0; i < 4; ++i) {
        const float inv = 1.f / rowsum[i0 + i];
        #pragma unroll
        for (int j = 0; j < 4; ++j)
            s3v[(size_t)bh * 4096 + (i0 + i) * 64 + j0 + j] = acc[i][j] * inv;
    }
}

// ---------------------------------------------------------------------------
// K6: W = z_star @ s3v (per bh, 64x64). grid=BH, 256 threads.
// ---------------------------------------------------------------------------
__global__ __launch_bounds__(256) void k_zmul(
    const float* __restrict__ Zs, const float* __restrict__ s3v,
    float* __restrict__ Wm)
{
    __shared__ float Ab[64][65];
    __shared__ float Bb[64][64];
    const int bh = blockIdx.x;
    const int tid = threadIdx.x;
    for (int idx = tid; idx < 4096; idx += 256) {
        Ab[idx >> 6][idx & 63] = Zs[(size_t)bh * 4096 + idx];
        Bb[idx >> 6][idx & 63] = s3v[(size_t)bh * 4096 + idx];
    }
    __syncthreads();
    const int tx = tid & 15, ty = tid >> 4;
    const int i0 = ty << 2, j0 = tx << 2;
    float acc[4][4] = {};
    for (int k = 0; k < 64; ++k) {
        float a[4], bb4[4];
        #pragma unroll
        for (int i = 0; i < 4; ++i) a[i] = Ab[i0 + i][k];
        #pragma unroll
        for (int j = 0; j < 4; ++j) bb4[j] = Bb[k][j0 + j];
        #pragma unroll
        for (int i = 0; i < 4; ++i)
            #pragma unroll
            for (int j = 0; j < 4; ++j) acc[i][j] = fmaf(a[i], bb4[j], acc[i][j]);
    }
    #pragma unroll
    for (int i = 0; i < 4; ++i)
        #pragma unroll
        for (int j = 0; j < 4; ++j)
            Wm[(size_t)bh * 4096 + (i0 + i) * 64 + j0 + j] = acc[i][j];
}

// ---------------------------------------------------------------------------
// K7: out_attn = softmax(q @ k_lm^T) @ W, per (b,h,l-tile of 64).
// s1 mask term is row-constant along the softmax axis (mask_lm==1) -> no-op.
// grid = (L/64, BH), 256 threads. Writes attn [B][L][H*HD].
// ---------------------------------------------------------------------------
__global__ __launch_bounds__(256) void k_attn_out(
    const float* __restrict__ Qt, const float* __restrict__ klm,
    const float* __restrict__ Wm, float* __restrict__ attn)
{
    const int lt = blockIdx.x;           // 0..63
    const int bh = blockIdx.y;           // 0..63
    const int b = bh >> 4, h = bh & 15;
    __shared__ float Qs[64][65];
    __shared__ float Ks[64][65];
    __shared__ float Ws[64][64];
    __shared__ float S[64][65];
    __shared__ float rsum[64];
    const int tid = threadIdx.x;
    const int tx = tid & 15, ty = tid >> 4;
    const int i0 = ty << 2, j0 = tx << 2;
    for (int idx = tid; idx < 4096; idx += 256) {
        const int r = idx >> 6, c2 = idx & 63;
        Qs[r][c2] = Qt[((size_t)bh * Ln + lt * 64 + r) * HDn + c2];
        Ks[r][c2] = klm[(size_t)bh * 4096 + idx];
        Ws[r][c2] = Wm[(size_t)bh * 4096 + idx];
    }
    __syncthreads();
    float sacc[4][4] = {};
    for (int k = 0; k < 64; ++k) {
        float a[4], bb4[4];
        #pragma unroll
        for (int i = 0; i < 4; ++i) a[i] = Qs[i0 + i][k];
        #pragma unroll
        for (int j = 0; j < 4; ++j) bb4[j] = Ks[j0 + j][k];
        #pragma unroll
        for (int i = 0; i < 4; ++i)
            #pragma unroll
            for (int j = 0; j < 4; ++j) sacc[i][j] = fmaf(a[i], bb4[j], sacc[i][j]);
    }
    #pragma unroll
    for (int i = 0; i < 4; ++i)
        #pragma unroll
        for (int j = 0; j < 4; ++j) S[i0 + i][j0 + j] = sacc[i][j];
    __syncthreads();
    if (tid < 64) {
        float mx = -1e30f;
        for (int j = 0; j < 64; ++j) mx = fmaxf(mx, S[tid][j]);
        float ps = 0.f;
        for (int j = 0; j < 64; ++j) {
            const float e = expf(S[tid][j] - mx);
            S[tid][j] = e;
            ps += e;
        }
        rsum[tid] = ps;
    }
    __syncthreads();
    float acc[4][4] = {};
    for (int k = 0; k < 64; ++k) {
        float a[4], bb4[4];
        #pragma unroll
        for (int i = 0; i < 4; ++i) a[i] = S[i0 + i][k];
        #pragma unroll
        for (int j = 0; j < 4; ++j) bb4[j] = Ws[k][j0 + j];
        #pragma unroll
        for (int i = 0; i < 4; ++i)
            #pragma unroll
            for (int j = 0; j < 4; ++j) acc[i][j] = fmaf(a[i], bb4[j], acc[i][j]);
    }
    #pragma unroll
    for (int i = 0; i < 4; ++i) {
        const float inv = 1.f / rsum[i0 + i];
        float4 v;
        v.x = acc[i][0] * inv; v.y = acc[i][1] * inv;
        v.z = acc[i][2] * inv; v.w = acc[i][3] * inv;
        const size_t row = (size_t)(b * Ln + lt * 64 + i0 + i);
        *(float4*)&attn[row * Dn + h * 64 + j0] = v;
    }
}

// ---------------------------------------------------------------------------
// K8: out = attn @ w_out^T + b_out  (M=16384, N=1024, K=1024)
// ---------------------------------------------------------------------------
__global__ __launch_bounds__(256) void k_out_gemm(
    const float* __restrict__ A, const float* __restrict__ w,
    const float* __restrict__ bias, float* __restrict__ out)
{
    __shared__ float As[8][132];
    __shared__ float Bs[8][132];
    const int tid = threadIdx.x;
    const int bm = blockIdx.x;          // 0..127
    const int bn = blockIdx.y;          // 0..7
    const int lrow = tid >> 1;
    const int lk4  = (tid & 1) << 2;
    const float* aP = A + (size_t)(bm * 128 + lrow) * Dn + lk4;
    const float* bP = w + (size_t)(bn * 128 + lrow) * Dn + lk4;
    const int tx = tid & 15, ty = tid >> 4;
    const int i0 = ty << 2, i1 = 64 + (ty << 2);
    const int j0 = tx << 2, j1 = 64 + (tx << 2);
    float acc[8][8] = {};
    float4 av = *(const float4*)aP;
    float4 bv = *(const float4*)bP;
    for (int kt = 0; kt < 128; ++kt) {
        __syncthreads();
        As[lk4 + 0][lrow] = av.x; As[lk4 + 1][lrow] = av.y;
        As[lk4 + 2][lrow] = av.z; As[lk4 + 3][lrow] = av.w;
        Bs[lk4 + 0][lrow] = bv.x; Bs[lk4 + 1][lrow] = bv.y;
        Bs[lk4 + 2][lrow] = bv.z; Bs[lk4 + 3][lrow] = bv.w;
        __syncthreads();
        if (kt < 127) {
            av = *(const float4*)(aP + (size_t)(kt + 1) * 8);
            bv = *(const float4*)(bP + (size_t)(kt + 1) * 8);
        }
        #pragma unroll
        for (int kk = 0; kk < 8; ++kk) {
            float ar[8], br[8];
            *(float4*)&ar[0] = *(const float4*)&As[kk][i0];
            *(float4*)&ar[4] = *(const float4*)&As[kk][i1];
            *(float4*)&br[0] = *(const float4*)&Bs[kk][j0];
            *(float4*)&br[4] = *(const float4*)&Bs[kk][j1];
            #pragma unroll
            for (int i = 0; i < 8; ++i)
                #pragma unroll
                for (int j = 0; j < 8; ++j)
                    acc[i][j] = fmaf(ar[i], br[j], acc[i][j]);
        }
    }
    #pragma unroll
    for (int i = 0; i < 8; ++i) {
        const int gm = bm * 128 + (i < 4 ? i0 + i : i1 + i - 4);
        #pragma unroll
        for (int jg = 0; jg < 2; ++jg) {
            const int gnb = bn * 128 + (jg ? j1 : j0);
            const float4 bb = *(const float4*)&bias[gnb];
            float4 v;
            v.x = acc[i][jg * 4 + 0] + bb.x;
            v.y = acc[i][jg * 4 + 1] + bb.y;
            v.z = acc[i][jg * 4 + 2] + bb.z;
            v.w = acc[i][jg * 4 + 3] + bb.w;
            *(float4*)&out[(size_t)gm * Dn + gnb] = v;
        }
    }
}

// ---------------------------------------------------------------------------
extern "C" void kernel_launch(void* const* d_in, const int* in_sizes, int n_in,
                              void* d_out, int out_size, void* d_ws, size_t ws_size,
                              hipStream_t stream)
{
    (void)in_sizes; (void)n_in; (void)out_size; (void)ws_size;
    const float* x    = (const float*)d_in[0];
    const float* mask = (const float*)d_in[1];
    const float* wkqv = (const float*)d_in[2];
    const float* wout = (const float*)d_in[3];
    const float* bout = (const float*)d_in[4];
    float* out = (float*)d_out;
    float* ws  = (float*)d_ws;

    float* Kt   = ws + OFF_K;
    float* Qt   = ws + OFF_Q;
    float* Vt   = ws + OFF_V;
    float* qlm  = ws + OFF_QLM;
    float* klm  = ws + OFF_KLM;
    float* s2   = ws + OFF_S2;
    float* zst  = ws + OFF_Z;
    float* s3v  = ws + OFF_S3V;
    float* Wm   = ws + OFF_W;
    int*   gmax = (int*)(ws + OFF_GM);
    float* attn = ws + OFF_ATTN;   // aliases Kt (dead after k_s3v)

    hipMemsetAsync(gmax, 0, 2 * sizeof(int), stream);
    k_kqv_gemm<<<dim3(Mn / 128, (3 * Dn) / 128), 256, 0, stream>>>(x, wkqv, mask, Kt, Qt, Vt);
    k_landmarks<<<BHn * NLn, 64, 0, stream>>>(Kt, Qt, mask, klm, qlm);
    k_s2<<<BHn, 64, 0, stream>>>(qlm, klm, s2, gmax);
    k_pinv<<<BHn, 256, 0, stream>>>(s2, gmax, zst);
    k_s3v<<<BHn, 256, 0, stream>>>(qlm, Kt, Vt, mask, s3v);
    k_zmul<<<BHn, 256, 0, stream>>>(zst, s3v, Wm);
    k_attn_out<<<dim3(Ln / 64, BHn), 256, 0, stream>>>(Qt, klm, Wm, attn);
    k_out_gemm<<<dim3(Mn / 128, Dn / 128), 256, 0, stream>>>(attn, wout, bout, out);
}

// Round 3
// 1932.261 us; speedup vs baseline: 1.2783x; 1.2783x over previous
//
#include <hip/hip_runtime.h>
#include <hip/hip_bf16.h>

// ---------------------------------------------------------------------------
// Nystromformer attention. bf16x3-split MFMA GEMMs, reg-staged LDS (no
// global_load_lds this round), ws footprint 212 MB (slab-packed x + aliasing).
// B=4, L=4096, D=1024, H=16, HD=64, NL=64, SEG=64, INV_ITERS=6
// ---------------------------------------------------------------------------

static constexpr int Bn  = 4;
static constexpr int Ln  = 4096;
static constexpr int Dn  = 1024;
static constexpr int Hn  = 16;
static constexpr int HDn = 64;
static constexpr int NLn = 64;
static constexpr int SEGn = 64;
static constexpr int BHn = Bn * Hn;     // 64
static constexpr int Mn  = Bn * Ln;     // 16384
static constexpr int NCH = 4;           // s3v chunks
static constexpr int SLAB = 2048;       // x-pack slab rows
#define NEG_BIG (-100000.0f)

// ---- workspace offsets (floats). Peak 212.0 MB. -------------------------
static constexpr size_t OFF_KT  = 0;          // Kt fp32 [64][4096][64]; later attn_h/attn_l packed
static constexpr size_t OFF_QT  = 16777216;
static constexpr size_t OFF_VT  = 33554432;
// Region A: x-slab (hi/lo) during gemms; Opart after.
static constexpr size_t OFF_XHS = 50331648;   // 1048576 (2048x1024 ushorts)
static constexpr size_t OFF_XLS = 51380224;   // 1048576
static constexpr size_t OFF_PO  = 50331648;   // Opart [64][4][64][64] = 1048576 (alias slab)
// Region B: wh/wl during gemms; packed wo + small buffers after.
static constexpr size_t OFF_WH  = 52428800;   // 1572864
static constexpr size_t OFF_WL  = 54001664;   // 1572864
static constexpr size_t OFF_WOH = 52428800;   // 524288  (alias wh)
static constexpr size_t OFF_WOL = 52953088;   // 524288
static constexpr size_t OFF_QLM = 53477376;   // 262144
static constexpr size_t OFF_KLM = 53739520;   // 262144
static constexpr size_t OFF_S2  = 54001664;   // 262144  (alias wl)
static constexpr size_t OFF_Z   = 54263808;   // 262144
static constexpr size_t OFF_S3V = 54525952;   // 262144
static constexpr size_t OFF_WM  = 54788096;   // 262144
static constexpr size_t OFF_PM  = 55050240;   // 16384
static constexpr size_t OFF_PS  = 55066624;   // 16384
static constexpr size_t OFF_GM  = 55574528;   // 64 (outside region B: memset'd at t=0)
// END = 55574592 floats = 212.04 MB

using bf16x8 = __attribute__((ext_vector_type(8))) short;
using f32x4  = __attribute__((ext_vector_type(4))) float;
using s16x4  = __attribute__((ext_vector_type(4))) short;

__device__ __forceinline__ unsigned short f2bf(float f) {
    unsigned int u = __float_as_uint(f);
    return (unsigned short)((u + 0x7fffu + ((u >> 16) & 1u)) >> 16);
}
__device__ __forceinline__ float bf2f(unsigned short h) {
    return __uint_as_float((unsigned int)h << 16);
}

// ---------------------------------------------------------------------------
// Pack: fp32 [rows][K] -> hi/lo bf16 in fragment-ordered 128x32 tiles.
// Tile (rt,kt): 4096 ushorts; slot s = (g*4+h)*16+rr holds row g*16+rr,
// k = h*8..h*8+7 (matches MFMA 16x16x32 A/B lane layout: row=lane&15,
// k=(lane>>4)*8+e). row0 = slab base row.
// ---------------------------------------------------------------------------
__global__ __launch_bounds__(256) void k_pack(
    const float* __restrict__ src, unsigned short* __restrict__ dh,
    unsigned short* __restrict__ dl, int row0)
{
    __shared__ float Ls[128][33];
    const int rt = blockIdx.x, kt = blockIdx.y;   // kt 0..31
    const int tid = threadIdx.x;
    #pragma unroll
    for (int p = 0; p < 4; ++p) {
        const int row = p * 32 + (tid >> 3);
        const int c4 = (tid & 7) * 4;
        const float4 v = *(const float4*)&src[(size_t)(row0 + rt * 128 + row) * 1024 + kt * 32 + c4];
        Ls[row][c4 + 0] = v.x; Ls[row][c4 + 1] = v.y;
        Ls[row][c4 + 2] = v.z; Ls[row][c4 + 3] = v.w;
    }
    __syncthreads();
    const size_t tb = (size_t)(rt * 32 + kt) * 4096;
    for (int s = tid; s < 512; s += 256) {
        const int rr = s & 15, gh = s >> 4;
        const int row = (gh >> 2) * 16 + rr, k0 = (gh & 3) * 8;
        bf16x8 hv, lv;
        #pragma unroll
        for (int e = 0; e < 8; ++e) {
            const float f = Ls[row][k0 + e];
            const unsigned short h = f2bf(f);
            hv[e] = (short)h;
            lv[e] = (short)f2bf(f - bf2f(h));
        }
        *(bf16x8*)&dh[tb + s * 8] = hv;
        *(bf16x8*)&dl[tb + s * 8] = lv;
    }
}

// ---------------------------------------------------------------------------
// bf16x3 MFMA GEMM core: 128x128 tile, 4 waves (64x64 each), BK=32.
// acc += Ah*Bh + Ah*Bl + Al*Bh over KT k-tiles. Reg-staged global->LDS,
// next-tile loads issued after 2nd barrier (latency hides under MFMA).
// ---------------------------------------------------------------------------
#define GEMM_CORE(Ah_, Al_, Bh_, Bl_, KT)                                      \
    __shared__ __attribute__((aligned(16))) char smem[32768];                  \
    const int tid = threadIdx.x;                                               \
    const int lane = tid & 63, wid = tid >> 6;                                 \
    const int bm = blockIdx.x, bn = blockIdx.y;                                \
    const int wrow = wid >> 1, wcol = wid & 1;                                 \
    const size_t mtb = (size_t)bm * (KT) * 8192;                               \
    const size_t ntb = (size_t)bn * (KT) * 8192;                               \
    const char* gsrc = wid == 0 ? (const char*)(Ah_) + mtb                     \
                     : wid == 1 ? (const char*)(Al_) + mtb                     \
                     : wid == 2 ? (const char*)(Bh_) + ntb                     \
                                : (const char*)(Bl_) + ntb;                    \
    gsrc += lane * 16;                                                         \
    char* ldst = smem + wid * 8192 + lane * 16;                                \
    const int lh = lane >> 4, lr = lane & 15;                                  \
    const int abase = (wrow * 16 + lh) * 256 + lr * 16;                        \
    const int bbase = (wcol * 16 + lh) * 256 + lr * 16;                        \
    f32x4 acc[4][4] = {};                                                      \
    float4 stg[8];                                                             \
    _Pragma("unroll")                                                          \
    for (int i = 0; i < 8; ++i) stg[i] = *(const float4*)(gsrc + i * 1024);    \
    for (int kt = 0; kt < (KT); ++kt) {                                        \
        __syncthreads();   /* prev tile readers done */                        \
        _Pragma("unroll")                                                      \
        for (int i = 0; i < 8; ++i) *(float4*)(ldst + i * 1024) = stg[i];      \
        __syncthreads();                                                       \
        if (kt + 1 < (KT)) {                                                   \
            const char* g2 = gsrc + (size_t)(kt + 1) * 8192;                   \
            _Pragma("unroll")                                                  \
            for (int i = 0; i < 8; ++i) stg[i] = *(const float4*)(g2 + i * 1024); \
        }                                                                      \
        bf16x8 ah[4], al[4], bh2[4], bl2[4];                                   \
        _Pragma("unroll")                                                      \
        for (int i = 0; i < 4; ++i) {                                          \
            ah[i] = *(const bf16x8*)(smem + abase + i * 1024);                 \
            al[i] = *(const bf16x8*)(smem + 8192 + abase + i * 1024);          \
        }                                                                      \
        _Pragma("unroll")                                                      \
        for (int j = 0; j < 4; ++j) {                                          \
            bh2[j] = *(const bf16x8*)(smem + 16384 + bbase + j * 1024);        \
            bl2[j] = *(const bf16x8*)(smem + 24576 + bbase + j * 1024);        \
        }                                                                      \
        _Pragma("unroll")                                                      \
        for (int i = 0; i < 4; ++i)                                            \
            _Pragma("unroll")                                                  \
            for (int j = 0; j < 4; ++j) {                                      \
                acc[i][j] = __builtin_amdgcn_mfma_f32_16x16x32_bf16(           \
                    ah[i], bh2[j], acc[i][j], 0, 0, 0);                        \
                acc[i][j] = __builtin_amdgcn_mfma_f32_16x16x32_bf16(           \
                    ah[i], bl2[j], acc[i][j], 0, 0, 0);                        \
                acc[i][j] = __builtin_amdgcn_mfma_f32_16x16x32_bf16(           \
                    al[i], bh2[j], acc[i][j], 0, 0, 0);                        \
            }                                                                  \
    }

// K1: kqv slab GEMM (2048 rows), scatter to Kt/Qt/Vt with mask (+1/8 on Q).
__global__ __launch_bounds__(256) void k_kqv_gemm(
    const unsigned short* __restrict__ xh, const unsigned short* __restrict__ xl,
    const unsigned short* __restrict__ wh, const unsigned short* __restrict__ wl,
    const float* __restrict__ mask,
    float* __restrict__ Kt, float* __restrict__ Qt, float* __restrict__ Vt,
    int row0)
{
    GEMM_CORE(xh, xl, wh, wl, 32)
    const int part = (bn * 128) >> 10;
    const int colbase = (bn * 128 + wcol * 64 + lr) & 1023;
    #pragma unroll
    for (int i = 0; i < 4; ++i) {
        #pragma unroll
        for (int r = 0; r < 4; ++r) {
            const int gm = row0 + bm * 128 + wrow * 64 + i * 16 + lh * 4 + r;
            const int b = gm >> 12, l = gm & 4095;
            const float mk = mask[b * Ln + l];
            #pragma unroll
            for (int j = 0; j < 4; ++j) {
                const int c = colbase + j * 16;
                const int h = c >> 6, d = c & 63;
                const size_t idx = ((size_t)(b * Hn + h) * Ln + l) * HDn + d;
                const float v = acc[i][j][r] * mk;
                if (part == 0)      Kt[idx] = v;
                else if (part == 1) Qt[idx] = v * 0.125f;
                else                Vt[idx] = v;
            }
        }
    }
}

// K8: out GEMM + bias.
__global__ __launch_bounds__(256) void k_out_gemm(
    const unsigned short* __restrict__ ah_, const unsigned short* __restrict__ al_,
    const unsigned short* __restrict__ bh_, const unsigned short* __restrict__ bl_,
    const float* __restrict__ bias, float* __restrict__ out)
{
    GEMM_CORE(ah_, al_, bh_, bl_, 32)
    #pragma unroll
    for (int i = 0; i < 4; ++i) {
        #pragma unroll
        for (int r = 0; r < 4; ++r) {
            const int gm = bm * 128 + wrow * 64 + i * 16 + lh * 4 + r;
            #pragma unroll
            for (int j = 0; j < 4; ++j) {
                const int gn = bn * 128 + wcol * 64 + j * 16 + lr;
                out[(size_t)gm * Dn + gn] = acc[i][j][r] + bias[gn];
            }
        }
    }
}

// ---------------------------------------------------------------------------
// K2: landmark means + zero gmax (block 0) before k_s2's atomicMax.
// ---------------------------------------------------------------------------
__global__ __launch_bounds__(64) void k_landmarks(
    const float* __restrict__ Kt, const float* __restrict__ Qt,
    const float* __restrict__ mask,
    float* __restrict__ klm, float* __restrict__ qlm, int* __restrict__ gmax)
{
    const int blk = blockIdx.x;
    const int m = blk & 63, bh = blk >> 6, b = bh >> 4;
    const int d = threadIdx.x;
    if (blk == 0 && d < 2) gmax[d] = 0;
    float mv = mask[b * Ln + m * SEGn + d];
    #pragma unroll
    for (int off = 32; off; off >>= 1) mv += __shfl_down(mv, off);
    const float denom = __shfl(mv, 0) + 1e-8f;
    const float* kp = Kt + ((size_t)bh * Ln + m * SEGn) * HDn + d;
    const float* qp = Qt + ((size_t)bh * Ln + m * SEGn) * HDn + d;
    float sk = 0.f, sq = 0.f;
    for (int j = 0; j < SEGn; ++j) {
        sk += kp[(size_t)j * HDn];
        sq += qp[(size_t)j * HDn];
    }
    klm[((size_t)bh * NLn + m) * HDn + d] = sk / denom;
    qlm[((size_t)bh * NLn + m) * HDn + d] = sq / denom;
}

// ---------------------------------------------------------------------------
// K3: s2 = softmax(q_lm @ k_lm^T) + global |row|/|col| sum maxes for pinv.
// ---------------------------------------------------------------------------
__global__ __launch_bounds__(64) void k_s2(
    const float* __restrict__ qlm, const float* __restrict__ klm,
    float* __restrict__ s2, int* __restrict__ gmax)
{
    const int bh = blockIdx.x;
    __shared__ float ql[64][65];
    __shared__ float kl[64][65];
    __shared__ float sr[64][65];
    const int t = threadIdx.x;
    for (int idx = t; idx < 4096; idx += 64) {
        ql[idx >> 6][idx & 63] = qlm[(size_t)bh * 4096 + idx];
        kl[idx >> 6][idx & 63] = klm[(size_t)bh * 4096 + idx];
    }
    __syncthreads();
    float mx = -1e30f;
    for (int mp = 0; mp < 64; ++mp) {
        float s = 0.f;
        #pragma unroll 8
        for (int d2 = 0; d2 < 64; ++d2) s = fmaf(ql[t][d2], kl[mp][d2], s);
        sr[t][mp] = s;
        mx = fmaxf(mx, s);
    }
    float sum = 0.f;
    for (int mp = 0; mp < 64; ++mp) {
        const float e = expf(sr[t][mp] - mx);
        sr[t][mp] = e;
        sum += e;
    }
    const float inv = 1.f / sum;
    float rs = 0.f;
    for (int mp = 0; mp < 64; ++mp) {
        const float v = sr[t][mp] * inv;
        sr[t][mp] = v;
        s2[(size_t)bh * 4096 + t * 64 + mp] = v;
        rs += fabsf(v);
    }
    __syncthreads();
    float cs = 0.f;
    for (int mm = 0; mm < 64; ++mm) cs += fabsf(sr[mm][t]);
    float rmax = rs, cmax = cs;
    #pragma unroll
    for (int off = 32; off; off >>= 1) {
        rmax = fmaxf(rmax, __shfl_down(rmax, off));
        cmax = fmaxf(cmax, __shfl_down(cmax, off));
    }
    if (t == 0) {
        atomicMax(&gmax[0], __float_as_int(rmax));
        atomicMax(&gmax[1], __float_as_int(cmax));
    }
}

// ---------------------------------------------------------------------------
// 64x64 fp32 matmul helper: C = scl * A @ (SUB ? dg*I - B : B).
// ---------------------------------------------------------------------------
template<int SUB>
__device__ __forceinline__ void mm64g(
    float* C, int ldc, const float* Ag, int lda,
    const float* Bm, int ldb, float dg, float scl)
{
    const int tid = threadIdx.x;
    const int tx = tid & 15, ty = tid >> 4;
    const int i0 = ty << 2, j0 = tx << 2;
    float acc[4][4] = {};
    for (int k = 0; k < 64; ++k) {
        float a[4], bb[4];
        #pragma unroll
        for (int i = 0; i < 4; ++i) a[i] = Ag[(size_t)(i0 + i) * lda + k];
        #pragma unroll
        for (int j = 0; j < 4; ++j) {
            float v = Bm[(size_t)k * ldb + j0 + j];
            if (SUB) v = ((k == j0 + j) ? dg : 0.0f) - v;
            bb[j] = v;
        }
        #pragma unroll
        for (int i = 0; i < 4; ++i)
            #pragma unroll
            for (int j = 0; j < 4; ++j) acc[i][j] = fmaf(a[i], bb[j], acc[i][j]);
    }
    __syncthreads();
    #pragma unroll
    for (int i = 0; i < 4; ++i)
        #pragma unroll
        for (int j = 0; j < 4; ++j) C[(size_t)(i0 + i) * ldc + j0 + j] = scl * acc[i][j];
    __syncthreads();
}

// ---------------------------------------------------------------------------
// K4: Moore-Penrose pinv, 6 Newton-Schulz iterations.
// ---------------------------------------------------------------------------
__global__ __launch_bounds__(256) void k_pinv(
    const float* __restrict__ s2, const int* __restrict__ gmax,
    float* __restrict__ zout)
{
    __shared__ float Zb[64][65];
    __shared__ float XZ[64][65];
    __shared__ float Tb[64][64];
    const int bh = blockIdx.x;
    const int tid = threadIdx.x;
    const float* X = s2 + (size_t)bh * 4096;
    const float scale = 1.0f / (__int_as_float(gmax[0]) * __int_as_float(gmax[1]));
    for (int idx = tid; idx < 4096; idx += 256) {
        const int i = idx >> 6, j = idx & 63;
        Zb[i][j] = X[j * 64 + i] * scale;
    }
    __syncthreads();
    for (int it = 0; it < 6; ++it) {
        mm64g<0>(&XZ[0][0], 65, X, 64, &Zb[0][0], 65, 0.f, 1.f);
        mm64g<1>(&Tb[0][0], 64, &XZ[0][0], 65, &XZ[0][0], 65, 7.f, 1.f);
        mm64g<1>(&Tb[0][0], 64, &XZ[0][0], 65, &Tb[0][0], 64, 15.f, 1.f);
        mm64g<1>(&Zb[0][0], 65, &Zb[0][0], 65, &Tb[0][0], 64, 13.f, 0.25f);
    }
    for (int idx = tid; idx < 4096; idx += 256)
        zout[(size_t)bh * 4096 + idx] = Zb[idx >> 6][idx & 63];
}

// ---------------------------------------------------------------------------
// K5a: s3v partial over 1024-row chunk, online softmax. grid (BH, NCH).
// ---------------------------------------------------------------------------
__global__ __launch_bounds__(256) void k_s3v_part(
    const float* __restrict__ qlm, const float* __restrict__ Kt,
    const float* __restrict__ Vt, const float* __restrict__ mask,
    float* __restrict__ Opart, float* __restrict__ mpart, float* __restrict__ spart)
{
    __shared__ float Ql[64][65];
    __shared__ float Ks[64][65];
    __shared__ float Vs[64][64];
    __shared__ float S[64][65];
    __shared__ float rowmax[64], rowsum[64], fac[64], mrow[64];
    const int bh = blockIdx.x, ch = blockIdx.y;
    const int b = bh >> 4;
    const int tid = threadIdx.x;
    const int tx = tid & 15, ty = tid >> 4;
    const int i0 = ty << 2, j0 = tx << 2;
    for (int idx = tid; idx < 4096; idx += 256)
        Ql[idx >> 6][idx & 63] = qlm[(size_t)bh * 4096 + idx];
    if (tid < 64) { rowmax[tid] = -1e30f; rowsum[tid] = 0.f; }
    float acc[4][4] = {};
    const int t0beg = ch * (Ln / NCH), t0end = t0beg + (Ln / NCH);
    for (int t0 = t0beg; t0 < t0end; t0 += 64) {
        __syncthreads();
        for (int idx = tid; idx < 4096; idx += 256) {
            const int r = idx >> 6, c2 = idx & 63;
            Ks[r][c2] = Kt[((size_t)bh * Ln + t0 + r) * HDn + c2];
            Vs[r][c2] = Vt[((size_t)bh * Ln + t0 + r) * HDn + c2];
        }
        if (tid < 64) mrow[tid] = mask[b * Ln + t0 + tid];
        __syncthreads();
        float sacc[4][4] = {};
        for (int k = 0; k < 64; ++k) {
            float a[4], bb4[4];
            #pragma unroll
            for (int i = 0; i < 4; ++i) a[i] = Ql[i0 + i][k];
            #pragma unroll
            for (int j = 0; j < 4; ++j) bb4[j] = Ks[j0 + j][k];
            #pragma unroll
            for (int i = 0; i < 4; ++i)
                #pragma unroll
                for (int j = 0; j < 4; ++j) sacc[i][j] = fmaf(a[i], bb4[j], sacc[i][j]);
        }
        #pragma unroll
        for (int i = 0; i < 4; ++i)
            #pragma unroll
            for (int j = 0; j < 4; ++j)
                S[i0 + i][j0 + j] = sacc[i][j] + (1.f - mrow[j0 + j]) * NEG_BIG;
        __syncthreads();
        if (tid < 64) {
            const int m = tid;
            float mx = -1e30f;
            for (int j = 0; j < 64; ++j) mx = fmaxf(mx, S[m][j]);
            const float nm = fmaxf(rowmax[m], mx);
            const float f = expf(rowmax[m] - nm);
            float ps = 0.f;
            for (int j = 0; j < 64; ++j) {
                const float e = expf(S[m][j] - nm);
                S[m][j] = e;
                ps += e;
            }
            rowsum[m] = rowsum[m] * f + ps;
            rowmax[m] = nm;
            fac[m] = f;
        }
        __syncthreads();
        #pragma unroll
        for (int i = 0; i < 4; ++i) {
            const float f = fac[i0 + i];
            #pragma unroll
            for (int j = 0; j < 4; ++j) acc[i][j] *= f;
        }
        for (int k = 0; k < 64; ++k) {
            float a[4], bb4[4];
            #pragma unroll
            for (int i = 0; i < 4; ++i) a[i] = S[i0 + i][k];
            #pragma unroll
            for (int j = 0; j < 4; ++j) bb4[j] = Vs[k][j0 + j];
            #pragma unroll
            for (int i = 0; i < 4; ++i)
                #pragma unroll
                for (int j = 0; j < 4; ++j) acc[i][j] = fmaf(a[i], bb4[j], acc[i][j]);
        }
    }
    const size_t ob = (size_t)(bh * NCH + ch) * 4096;
    #pragma unroll
    for (int i = 0; i < 4; ++i)
        #pragma unroll
        for (int j = 0; j < 4; ++j)
            Opart[ob + (i0 + i) * 64 + j0 + j] = acc[i][j];
    if (tid < 64) {
        mpart[(bh * NCH + ch) * 64 + tid] = rowmax[tid];
        spart[(bh * NCH + ch) * 64 + tid] = rowsum[tid];
    }
}

// K5b: merge chunks.
__global__ __launch_bounds__(256) void k_s3v_merge(
    const float* __restrict__ Opart, const float* __restrict__ mpart,
    const float* __restrict__ spart, float* __restrict__ s3v)
{
    const int bh = blockIdx.x, tid = threadIdx.x;
    const int r = tid >> 2, c0 = (tid & 3) * 16;
    float e[NCH];
    float M = -1e30f;
    #pragma unroll
    for (int c = 0; c < NCH; ++c) {
        e[c] = mpart[(bh * NCH + c) * 64 + r];
        M = fmaxf(M, e[c]);
    }
    float S = 0.f;
    #pragma unroll
    for (int c = 0; c < NCH; ++c) {
        e[c] = expf(e[c] - M);
        S += spart[(bh * NCH + c) * 64 + r] * e[c];
    }
    const float invS = 1.f / S;
    for (int col = c0; col < c0 + 16; ++col) {
        float o = 0.f;
        #pragma unroll
        for (int c = 0; c < NCH; ++c)
            o += Opart[(size_t)(bh * NCH + c) * 4096 + r * 64 + col] * e[c];
        s3v[(size_t)bh * 4096 + r * 64 + col] = o * invS;
    }
}

// ---------------------------------------------------------------------------
// K6: W = z_star @ s3v (per bh, 64x64).
// ---------------------------------------------------------------------------
__global__ __launch_bounds__(256) void k_zmul(
    const float* __restrict__ Zs, const float* __restrict__ s3v,
    float* __restrict__ Wm)
{
    __shared__ float Ab[64][65];
    __shared__ float Bb[64][64];
    const int bh = blockIdx.x;
    const int tid = threadIdx.x;
    for (int idx = tid; idx < 4096; idx += 256) {
        Ab[idx >> 6][idx & 63] = Zs[(size_t)bh * 4096 + idx];
        Bb[idx >> 6][idx & 63] = s3v[(size_t)bh * 4096 + idx];
    }
    __syncthreads();
    const int tx = tid & 15, ty = tid >> 4;
    const int i0 = ty << 2, j0 = tx << 2;
    float acc[4][4] = {};
    for (int k = 0; k < 64; ++k) {
        float a[4], bb4[4];
        #pragma unroll
        for (int i = 0; i < 4; ++i) a[i] = Ab[i0 + i][k];
        #pragma unroll
        for (int j = 0; j < 4; ++j) bb4[j] = Bb[k][j0 + j];
        #pragma unroll
        for (int i = 0; i < 4; ++i)
            #pragma unroll
            for (int j = 0; j < 4; ++j) acc[i][j] = fmaf(a[i], bb4[j], acc[i][j]);
    }
    #pragma unroll
    for (int i = 0; i < 4; ++i)
        #pragma unroll
        for (int j = 0; j < 4; ++j)
            Wm[(size_t)bh * 4096 + (i0 + i) * 64 + j0 + j] = acc[i][j];
}

// ---------------------------------------------------------------------------
// K7: out_attn = softmax(q @ k_lm^T) @ W -> packed hi/lo bf16 in GEMM2's
// fragment-ordered tile layout.
// ---------------------------------------------------------------------------
__global__ __launch_bounds__(256) void k_attn_out(
    const float* __restrict__ Qt, const float* __restrict__ klm,
    const float* __restrict__ Wm,
    unsigned short* __restrict__ ah, unsigned short* __restrict__ al)
{
    const int lt = blockIdx.x;
    const int bh = blockIdx.y;
    const int b = bh >> 4, h = bh & 15;
    __shared__ float Qs[64][65];
    __shared__ float Ks[64][65];
    __shared__ float Ws[64][64];
    __shared__ float S[64][65];
    __shared__ float rsum[64];
    const int tid = threadIdx.x;
    const int tx = tid & 15, ty = tid >> 4;
    const int i0 = ty << 2, j0 = tx << 2;
    for (int idx = tid; idx < 4096; idx += 256) {
        const int r = idx >> 6, c2 = idx & 63;
        Qs[r][c2] = Qt[((size_t)bh * Ln + lt * 64 + r) * HDn + c2];
        Ks[r][c2] = klm[(size_t)bh * 4096 + idx];
        Ws[r][c2] = Wm[(size_t)bh * 4096 + idx];
    }
    __syncthreads();
    float sacc[4][4] = {};
    for (int k = 0; k < 64; ++k) {
        float a[4], bb4[4];
        #pragma unroll
        for (int i = 0; i < 4; ++i) a[i] = Qs[i0 + i][k];
        #pragma unroll
        for (int j = 0; j < 4; ++j) bb4[j] = Ks[j0 + j][k];
        #pragma unroll
        for (int i = 0; i < 4; ++i)
            #pragma unroll
            for (int j = 0; j < 4; ++j) sacc[i][j] = fmaf(a[i], bb4[j], sacc[i][j]);
    }
    #pragma unroll
    for (int i = 0; i < 4; ++i)
        #pragma unroll
        for (int j = 0; j < 4; ++j) S[i0 + i][j0 + j] = sacc[i][j];
    __syncthreads();
    if (tid < 64) {
        float mx = -1e30f;
        for (int j = 0; j < 64; ++j) mx = fmaxf(mx, S[tid][j]);
        float ps = 0.f;
        for (int j = 0; j < 64; ++j) {
            const float e = expf(S[tid][j] - mx);
            S[tid][j] = e;
            ps += e;
        }
        rsum[tid] = ps;
    }
    __syncthreads();
    float acc[4][4] = {};
    for (int k = 0; k < 64; ++k) {
        float a[4], bb4[4];
        #pragma unroll
        for (int i = 0; i < 4; ++i) a[i] = S[i0 + i][k];
        #pragma unroll
        for (int j = 0; j < 4; ++j) bb4[j] = Ws[k][j0 + j];
        #pragma unroll
        for (int i = 0; i < 4; ++i)
            #pragma unroll
            for (int j = 0; j < 4; ++j) acc[i][j] = fmaf(a[i], bb4[j], acc[i][j]);
    }
    const int kd = h * 64 + j0;
    const int kt2 = kd >> 5, hh = (kd & 31) >> 3, k7 = kd & 7;
    #pragma unroll
    for (int i = 0; i < 4; ++i) {
        const float inv = 1.f / rsum[i0 + i];
        const int m = b * Ln + lt * 64 + i0 + i;
        const int mt = m >> 7, mrow = m & 127;
        const int g = mrow >> 4, rr = mrow & 15;
        const size_t off = (size_t)(mt * 32 + kt2) * 4096
                         + ((g * 4 + hh) * 16 + rr) * 8 + k7;
        s16x4 hv, lv;
        #pragma unroll
        for (int jj = 0; jj < 4; ++jj) {
            const float f = acc[i][jj] * inv;
            const unsigned short hb = f2bf(f);
            hv[jj] = (short)hb;
            lv[jj] = (short)f2bf(f - bf2f(hb));
        }
        *(s16x4*)&ah[off] = hv;
        *(s16x4*)&al[off] = lv;
    }
}

// ---------------------------------------------------------------------------
extern "C" void kernel_launch(void* const* d_in, const int* in_sizes, int n_in,
                              void* d_out, int out_size, void* d_ws, size_t ws_size,
                              hipStream_t stream)
{
    (void)in_sizes; (void)n_in; (void)out_size; (void)ws_size;
    const float* x    = (const float*)d_in[0];
    const float* mask = (const float*)d_in[1];
    const float* wkqv = (const float*)d_in[2];
    const float* wout = (const float*)d_in[3];
    const float* bout = (const float*)d_in[4];
    float* out = (float*)d_out;
    float* ws  = (float*)d_ws;

    float* Kt   = ws + OFF_KT;
    float* Qt   = ws + OFF_QT;
    float* Vt   = ws + OFF_VT;
    float* qlm  = ws + OFF_QLM;
    float* klm  = ws + OFF_KLM;
    float* s2   = ws + OFF_S2;
    float* zst  = ws + OFF_Z;
    float* s3v  = ws + OFF_S3V;
    float* Wm   = ws + OFF_WM;
    int*   gmax = (int*)(ws + OFF_GM);
    float* mpart = ws + OFF_PM;
    float* spart = ws + OFF_PS;
    float* Opart = ws + OFF_PO;
    unsigned short* xhs = (unsigned short*)(ws + OFF_XHS);
    unsigned short* xls = (unsigned short*)(ws + OFF_XLS);
    unsigned short* wh  = (unsigned short*)(ws + OFF_WH);
    unsigned short* wl  = (unsigned short*)(ws + OFF_WL);
    unsigned short* woh = (unsigned short*)(ws + OFF_WOH);
    unsigned short* wol = (unsigned short*)(ws + OFF_WOL);
    unsigned short* attn_h = (unsigned short*)(ws + OFF_KT);
    unsigned short* attn_l = (unsigned short*)(ws + OFF_KT + 8388608);

    hipMemsetAsync(gmax, 0, 2 * sizeof(int), stream);
    k_pack<<<dim3(24, 32), 256, 0, stream>>>(wkqv, wh, wl, 0);
    for (int s = 0; s < Mn / SLAB; ++s) {
        k_pack<<<dim3(SLAB / 128, 32), 256, 0, stream>>>(x, xhs, xls, s * SLAB);
        k_kqv_gemm<<<dim3(SLAB / 128, 24), 256, 0, stream>>>(
            xhs, xls, wh, wl, mask, Kt, Qt, Vt, s * SLAB);
    }
    k_pack<<<dim3(8, 32), 256, 0, stream>>>(wout, woh, wol, 0);
    k_landmarks<<<BHn * NLn, 64, 0, stream>>>(Kt, Qt, mask, klm, qlm, gmax);
    k_s2<<<BHn, 64, 0, stream>>>(qlm, klm, s2, gmax);
    k_pinv<<<BHn, 256, 0, stream>>>(s2, gmax, zst);
    k_s3v_part<<<dim3(BHn, NCH), 256, 0, stream>>>(qlm, Kt, Vt, mask, Opart, mpart, spart);
    k_s3v_merge<<<BHn, 256, 0, stream>>>(Opart, mpart, spart, s3v);
    k_zmul<<<BHn, 256, 0, stream>>>(zst, s3v, Wm);
    k_attn_out<<<dim3(Ln / 64, BHn), 256, 0, stream>>>(Qt, klm, Wm, attn_h, attn_l);
    k_out_gemm<<<dim3(Mn / 128, 8), 256, 0, stream>>>(attn_h, attn_l, woh, wol, bout, out);
}

// Round 4
// 1157.488 us; speedup vs baseline: 2.1339x; 1.6694x over previous
//
#include <hip/hip_runtime.h>
#include <hip/hip_bf16.h>

// ---------------------------------------------------------------------------
// Nystromformer attention. bf16x3-split 32x32x16 MFMA GEMMs with in-kernel
// fp32->hi/lo conversion for A operands; weights pre-packed.
// B=4, L=4096, D=1024, H=16, HD=64, NL=64, SEG=64, INV_ITERS=6
// ---------------------------------------------------------------------------

static constexpr int Bn  = 4;
static constexpr int Ln  = 4096;
static constexpr int Dn  = 1024;
static constexpr int Hn  = 16;
static constexpr int HDn = 64;
static constexpr int NLn = 64;
static constexpr int SEGn = 64;
static constexpr int BHn = Bn * Hn;     // 64
static constexpr int Mn  = Bn * Ln;     // 16384
static constexpr int NCH = 8;           // s3v chunks
#define NEG_BIG (-100000.0f)

// ---- workspace offsets (floats). END = 55115840 fl = 210.3 MB -----------
static constexpr size_t OFF_KT  = 0;          // Kt fp32; later attn fp32 (alias)
static constexpr size_t OFF_QT  = 16777216;
static constexpr size_t OFF_VT  = 33554432;   // Vt fp32; later woh/wol packed
static constexpr size_t OFF_WOH = 33554432;   // 524288 fl (alias Vt, packed after s3v)
static constexpr size_t OFF_WOL = 34078720;   // 524288 fl
static constexpr size_t OFF_WH  = 50331648;   // wkqv hi packed, 1572864 fl
static constexpr size_t OFF_WL  = 51904512;   // 1572864 fl
static constexpr size_t OFF_PO  = 50331648;   // Opart [64][8][4096] = 2097152 fl (alias wh/wl)
static constexpr size_t OFF_QLM = 53477376;   // 262144
static constexpr size_t OFF_KLM = 53739520;
static constexpr size_t OFF_S2  = 54001664;
static constexpr size_t OFF_Z   = 54263808;
static constexpr size_t OFF_S3V = 54525952;
static constexpr size_t OFF_WM  = 54788096;
static constexpr size_t OFF_PM  = 55050240;   // 32768
static constexpr size_t OFF_PS  = 55083008;   // 32768
static constexpr size_t OFF_GM  = 55115776;   // 64

using bf16x8 = __attribute__((ext_vector_type(8))) short;
using f32x16 = __attribute__((ext_vector_type(16))) float;

__device__ __forceinline__ unsigned short f2bf(float f) {
    unsigned int u = __float_as_uint(f);
    return (unsigned short)((u + 0x7fffu + ((u >> 16) & 1u)) >> 16);
}
__device__ __forceinline__ float bf2f(unsigned short h) {
    return __uint_as_float((unsigned int)h << 16);
}

// ---------------------------------------------------------------------------
// Weight pack: fp32 [rows][1024] -> hi/lo bf16 in 32x32x16-fragment-ordered
// 128x32 tiles. Tile (rt,kt), ushort index u = s*8+e with s = g*128+kk*64+l:
// row = g*32 + (l&31), k = kk*16 + ((l>>5)&1)*8 + e.
// hi = truncated bf16, lo = bf16(f - hi).
// ---------------------------------------------------------------------------
__global__ __launch_bounds__(256) void k_pack(
    const float* __restrict__ src, unsigned short* __restrict__ dh,
    unsigned short* __restrict__ dl)
{
    __shared__ float Ls[128][33];
    const int rt = blockIdx.x, kt = blockIdx.y;   // kt 0..31
    const int tid = threadIdx.x;
    #pragma unroll
    for (int p = 0; p < 4; ++p) {
        const int row = p * 32 + (tid >> 3);
        const int c4 = (tid & 7) * 4;
        const float4 v = *(const float4*)&src[(size_t)(rt * 128 + row) * 1024 + kt * 32 + c4];
        Ls[row][c4 + 0] = v.x; Ls[row][c4 + 1] = v.y;
        Ls[row][c4 + 2] = v.z; Ls[row][c4 + 3] = v.w;
    }
    __syncthreads();
    const size_t tb = (size_t)(rt * 32 + kt) * 4096;
    for (int s = tid; s < 512; s += 256) {
        const int g = s >> 7, kk = (s >> 6) & 1, l = s & 63;
        const int row = g * 32 + (l & 31);
        const int k0 = kk * 16 + ((l >> 5) & 1) * 8;
        bf16x8 hv, lv;
        #pragma unroll
        for (int e = 0; e < 8; ++e) {
            const float f = Ls[row][k0 + e];
            const unsigned int u = __float_as_uint(f);
            const unsigned short h = (unsigned short)(u >> 16);   // truncate
            hv[e] = (short)h;
            lv[e] = (short)f2bf(f - bf2f(h));
        }
        *(bf16x8*)&dh[tb + s * 8] = hv;
        *(bf16x8*)&dl[tb + s * 8] = lv;
    }
}

// ---------------------------------------------------------------------------
// bf16x3 32x32x16 MFMA GEMM core. 128x128 tile, 4 waves (64x64 each), BK=32.
// A: fp32 row-major (lda=1024), converted to hi/lo bf16 during staging.
// B: pre-packed hi/lo tiles. acc += Ah*Bh + Ah*Bl + Al*Bh.
// LDS: Ah[0,8K) Al[8K,16K) Bh[16K,24K) Bl[24K,32K).
// XCD-chunked swizzle on 1-D grid (gridDim.x % 8 == 0).
// ---------------------------------------------------------------------------
#define CVT_A(p)                                                               \
    {                                                                          \
        const unsigned int u0 = __float_as_uint(sA[p].x);                      \
        const unsigned int u1 = __float_as_uint(sA[p].y);                      \
        const unsigned int u2 = __float_as_uint(sA[p].z);                      \
        const unsigned int u3 = __float_as_uint(sA[p].w);                      \
        hA[p].x = (u0 >> 16) | (u1 & 0xffff0000u);                             \
        hA[p].y = (u2 >> 16) | (u3 & 0xffff0000u);                             \
        const float l0 = sA[p].x - __uint_as_float(u0 & 0xffff0000u);          \
        const float l1 = sA[p].y - __uint_as_float(u1 & 0xffff0000u);          \
        const float l2 = sA[p].z - __uint_as_float(u2 & 0xffff0000u);          \
        const float l3 = sA[p].w - __uint_as_float(u3 & 0xffff0000u);          \
        lA[p].x = (__float_as_uint(l0) >> 16) | (__float_as_uint(l1) & 0xffff0000u); \
        lA[p].y = (__float_as_uint(l2) >> 16) | (__float_as_uint(l3) & 0xffff0000u); \
    }

#define GEMM32_CORE(Afp_, Bh_, Bl_, NNB)                                       \
    __shared__ __attribute__((aligned(16))) char smem[32768];                  \
    const int tid = threadIdx.x;                                               \
    const int lane = tid & 63, wid = tid >> 6;                                 \
    const int cpx = gridDim.x >> 3;                                            \
    const int wg = (blockIdx.x & 7) * cpx + (blockIdx.x >> 3);                 \
    const int bm = wg / (NNB), bn = wg % (NNB);                                \
    const int wrow = wid >> 1, wcol = wid & 1;                                 \
    /* staging maps: A float4 f: row=f>>3 fc=f&7 ; B float4 f */               \
    int aoffB[4]; const float* aptr[4];                                        \
    const unsigned short *bsrc[4]; int boff[4];                                \
    _Pragma("unroll")                                                          \
    for (int p = 0; p < 4; ++p) {                                              \
        const int f = p * 256 + tid;                                           \
        const int row = f >> 3, fc = f & 7;                                    \
        aptr[p] = (Afp_) + (size_t)(bm * 128 + row) * 1024 + fc * 4;           \
        aoffB[p] = ((((row >> 5) * 2 + (fc >> 2)) * 64 +                        \
                     ((fc >> 1) & 1) * 32 + (row & 31)) * 8 + (fc & 1) * 4) * 2; \
        const int fb = p * 256 + tid;                                          \
        const int half = fb >> 9;           /* 0: hi buf, 1: lo buf */         \
        const int fi = fb & 511;                                               \
        bsrc[p] = (half ? (Bl_) : (Bh_)) + fi * 8;                             \
        boff[p] = 16384 + half * 8192 + fi * 16;                               \
    }                                                                          \
    const size_t btb = (size_t)bn * 32 * 4096;                                 \
    f32x16 acc[2][2] = {};                                                     \
    float4 sA[4]; uint2 hA[4], lA[4]; float4 sB[4];                            \
    _Pragma("unroll")                                                          \
    for (int p = 0; p < 4; ++p) {                                              \
        sA[p] = *(const float4*)(aptr[p]);                                     \
        sB[p] = *(const float4*)(bsrc[p] + btb);                               \
        CVT_A(p)                                                               \
    }                                                                          \
    for (int kt = 0; kt < 32; ++kt) {                                          \
        __syncthreads();                                                       \
        _Pragma("unroll")                                                      \
        for (int p = 0; p < 4; ++p) {                                          \
            *(uint2*)(smem + aoffB[p]) = hA[p];                                \
            *(uint2*)(smem + 8192 + aoffB[p]) = lA[p];                         \
            *(float4*)(smem + boff[p]) = sB[p];                                \
        }                                                                      \
        __syncthreads();                                                       \
        if (kt + 1 < 32) {                                                     \
            _Pragma("unroll")                                                  \
            for (int p = 0; p < 4; ++p) {                                      \
                sA[p] = *(const float4*)(aptr[p] + (kt + 1) * 32);             \
                sB[p] = *(const float4*)(bsrc[p] + btb + (size_t)(kt + 1) * 4096); \
            }                                                                  \
        }                                                                      \
        _Pragma("unroll")                                                      \
        for (int kk = 0; kk < 2; ++kk) {                                       \
            bf16x8 fa[2], fal[2], fb2[2], fbl[2];                              \
            _Pragma("unroll")                                                  \
            for (int ti = 0; ti < 2; ++ti) {                                   \
                const int o = (((wrow * 2 + ti) * 2 + kk) << 10) + lane * 16;  \
                fa[ti]  = *(const bf16x8*)(smem + o);                          \
                fal[ti] = *(const bf16x8*)(smem + 8192 + o);                   \
            }                                                                  \
            _Pragma("unroll")                                                  \
            for (int tj = 0; tj < 2; ++tj) {                                   \
                const int o = (((wcol * 2 + tj) * 2 + kk) << 10) + lane * 16;  \
                fb2[tj] = *(const bf16x8*)(smem + 16384 + o);                  \
                fbl[tj] = *(const bf16x8*)(smem + 24576 + o);                  \
            }                                                                  \
            _Pragma("unroll")                                                  \
            for (int ti = 0; ti < 2; ++ti)                                     \
                _Pragma("unroll")                                              \
                for (int tj = 0; tj < 2; ++tj) {                               \
                    acc[ti][tj] = __builtin_amdgcn_mfma_f32_32x32x16_bf16(     \
                        fa[ti], fb2[tj], acc[ti][tj], 0, 0, 0);                \
                    acc[ti][tj] = __builtin_amdgcn_mfma_f32_32x32x16_bf16(     \
                        fa[ti], fbl[tj], acc[ti][tj], 0, 0, 0);                \
                    acc[ti][tj] = __builtin_amdgcn_mfma_f32_32x32x16_bf16(     \
                        fal[ti], fb2[tj], acc[ti][tj], 0, 0, 0);               \
                }                                                              \
        }                                                                      \
        if (kt + 1 < 32) {                                                     \
            _Pragma("unroll")                                                  \
            for (int p = 0; p < 4; ++p) CVT_A(p)                               \
        }                                                                      \
    }

// K1: kqv GEMM (A = x fp32), scatter to Kt/Qt/Vt with mask (+1/8 on Q).
__global__ __launch_bounds__(256) void k_kqv_gemm(
    const float* __restrict__ x,
    const unsigned short* __restrict__ wh, const unsigned short* __restrict__ wl,
    const float* __restrict__ mask,
    float* __restrict__ Kt, float* __restrict__ Qt, float* __restrict__ Vt)
{
    GEMM32_CORE(x, wh, wl, 24)
    const int part = bn >> 3;
    #pragma unroll
    for (int ti = 0; ti < 2; ++ti) {
        #pragma unroll
        for (int tj = 0; tj < 2; ++tj) {
            const int col = (bn * 128 + wcol * 64 + tj * 32 + (lane & 31)) & 1023;
            const int h = col >> 6, d = col & 63;
            #pragma unroll
            for (int r = 0; r < 16; ++r) {
                const int row = bm * 128 + wrow * 64 + ti * 32
                              + (r & 3) + 8 * (r >> 2) + 4 * (lane >> 5);
                const int b = row >> 12, l = row & 4095;
                const float mk = mask[b * Ln + l];
                const size_t idx = ((size_t)(b * Hn + h) * Ln + l) * HDn + d;
                const float v = acc[ti][tj][r] * mk;
                if (part == 0)      Kt[idx] = v;
                else if (part == 1) Qt[idx] = v * 0.125f;
                else                Vt[idx] = v;
            }
        }
    }
}

// K8: out GEMM (A = attn fp32) + bias.
__global__ __launch_bounds__(256) void k_out_gemm(
    const float* __restrict__ attn,
    const unsigned short* __restrict__ woh, const unsigned short* __restrict__ wol,
    const float* __restrict__ bias, float* __restrict__ out)
{
    GEMM32_CORE(attn, woh, wol, 8)
    #pragma unroll
    for (int ti = 0; ti < 2; ++ti) {
        #pragma unroll
        for (int tj = 0; tj < 2; ++tj) {
            const int col = bn * 128 + wcol * 64 + tj * 32 + (lane & 31);
            const float bb = bias[col];
            #pragma unroll
            for (int r = 0; r < 16; ++r) {
                const int row = bm * 128 + wrow * 64 + ti * 32
                              + (r & 3) + 8 * (r >> 2) + 4 * (lane >> 5);
                out[(size_t)row * Dn + col] = acc[ti][tj][r] + bb;
            }
        }
    }
}

// ---------------------------------------------------------------------------
// K2: landmark means + zero gmax.
// ---------------------------------------------------------------------------
__global__ __launch_bounds__(64) void k_landmarks(
    const float* __restrict__ Kt, const float* __restrict__ Qt,
    const float* __restrict__ mask,
    float* __restrict__ klm, float* __restrict__ qlm, int* __restrict__ gmax)
{
    const int blk = blockIdx.x;
    const int m = blk & 63, bh = blk >> 6, b = bh >> 4;
    const int d = threadIdx.x;
    if (blk == 0 && d < 2) gmax[d] = 0;
    float mv = mask[b * Ln + m * SEGn + d];
    #pragma unroll
    for (int off = 32; off; off >>= 1) mv += __shfl_down(mv, off);
    const float denom = __shfl(mv, 0) + 1e-8f;
    const float* kp = Kt + ((size_t)bh * Ln + m * SEGn) * HDn + d;
    const float* qp = Qt + ((size_t)bh * Ln + m * SEGn) * HDn + d;
    float sk = 0.f, sq = 0.f;
    for (int j = 0; j < SEGn; ++j) {
        sk += kp[(size_t)j * HDn];
        sq += qp[(size_t)j * HDn];
    }
    klm[((size_t)bh * NLn + m) * HDn + d] = sk / denom;
    qlm[((size_t)bh * NLn + m) * HDn + d] = sq / denom;
}

// ---------------------------------------------------------------------------
// K3: s2 = softmax(q_lm @ k_lm^T) + global |row|/|col| sum maxes.
// ---------------------------------------------------------------------------
__global__ __launch_bounds__(64) void k_s2(
    const float* __restrict__ qlm, const float* __restrict__ klm,
    float* __restrict__ s2, int* __restrict__ gmax)
{
    const int bh = blockIdx.x;
    __shared__ float ql[64][65];
    __shared__ float kl[64][65];
    __shared__ float sr[64][65];
    const int t = threadIdx.x;
    for (int idx = t; idx < 4096; idx += 64) {
        ql[idx >> 6][idx & 63] = qlm[(size_t)bh * 4096 + idx];
        kl[idx >> 6][idx & 63] = klm[(size_t)bh * 4096 + idx];
    }
    __syncthreads();
    float mx = -1e30f;
    for (int mp = 0; mp < 64; ++mp) {
        float s = 0.f;
        #pragma unroll 8
        for (int d2 = 0; d2 < 64; ++d2) s = fmaf(ql[t][d2], kl[mp][d2], s);
        sr[t][mp] = s;
        mx = fmaxf(mx, s);
    }
    float sum = 0.f;
    for (int mp = 0; mp < 64; ++mp) {
        const float e = expf(sr[t][mp] - mx);
        sr[t][mp] = e;
        sum += e;
    }
    const float inv = 1.f / sum;
    float rs = 0.f;
    for (int mp = 0; mp < 64; ++mp) {
        const float v = sr[t][mp] * inv;
        sr[t][mp] = v;
        s2[(size_t)bh * 4096 + t * 64 + mp] = v;
        rs += fabsf(v);
    }
    __syncthreads();
    float cs = 0.f;
    for (int mm = 0; mm < 64; ++mm) cs += fabsf(sr[mm][t]);
    float rmax = rs, cmax = cs;
    #pragma unroll
    for (int off = 32; off; off >>= 1) {
        rmax = fmaxf(rmax, __shfl_down(rmax, off));
        cmax = fmaxf(cmax, __shfl_down(cmax, off));
    }
    if (t == 0) {
        atomicMax(&gmax[0], __float_as_int(rmax));
        atomicMax(&gmax[1], __float_as_int(cmax));
    }
}

// ---------------------------------------------------------------------------
// 64x64 fp32 matmul helper: C = scl * A @ (SUB ? dg*I - B : B).
// ---------------------------------------------------------------------------
template<int SUB>
__device__ __forceinline__ void mm64g(
    float* C, int ldc, const float* Ag, int lda,
    const float* Bm, int ldb, float dg, float scl)
{
    const int tid = threadIdx.x;
    const int tx = tid & 15, ty = tid >> 4;
    const int i0 = ty << 2, j0 = tx << 2;
    float acc[4][4] = {};
    for (int k = 0; k < 64; ++k) {
        float a[4], bb[4];
        #pragma unroll
        for (int i = 0; i < 4; ++i) a[i] = Ag[(size_t)(i0 + i) * lda + k];
        #pragma unroll
        for (int j = 0; j < 4; ++j) {
            float v = Bm[(size_t)k * ldb + j0 + j];
            if (SUB) v = ((k == j0 + j) ? dg : 0.0f) - v;
            bb[j] = v;
        }
        #pragma unroll
        for (int i = 0; i < 4; ++i)
            #pragma unroll
            for (int j = 0; j < 4; ++j) acc[i][j] = fmaf(a[i], bb[j], acc[i][j]);
    }
    __syncthreads();
    #pragma unroll
    for (int i = 0; i < 4; ++i)
        #pragma unroll
        for (int j = 0; j < 4; ++j) C[(size_t)(i0 + i) * ldc + j0 + j] = scl * acc[i][j];
    __syncthreads();
}

// ---------------------------------------------------------------------------
// K4: Moore-Penrose pinv, 6 Newton-Schulz iterations.
// ---------------------------------------------------------------------------
__global__ __launch_bounds__(256) void k_pinv(
    const float* __restrict__ s2, const int* __restrict__ gmax,
    float* __restrict__ zout)
{
    __shared__ float Zb[64][65];
    __shared__ float XZ[64][65];
    __shared__ float Tb[64][64];
    const int bh = blockIdx.x;
    const int tid = threadIdx.x;
    const float* X = s2 + (size_t)bh * 4096;
    const float scale = 1.0f / (__int_as_float(gmax[0]) * __int_as_float(gmax[1]));
    for (int idx = tid; idx < 4096; idx += 256) {
        const int i = idx >> 6, j = idx & 63;
        Zb[i][j] = X[j * 64 + i] * scale;
    }
    __syncthreads();
    for (int it = 0; it < 6; ++it) {
        mm64g<0>(&XZ[0][0], 65, X, 64, &Zb[0][0], 65, 0.f, 1.f);
        mm64g<1>(&Tb[0][0], 64, &XZ[0][0], 65, &XZ[0][0], 65, 7.f, 1.f);
        mm64g<1>(&Tb[0][0], 64, &XZ[0][0], 65, &Tb[0][0], 64, 15.f, 1.f);
        mm64g<1>(&Zb[0][0], 65, &Zb[0][0], 65, &Tb[0][0], 64, 13.f, 0.25f);
    }
    for (int idx = tid; idx < 4096; idx += 256)
        zout[(size_t)bh * 4096 + idx] = Zb[idx >> 6][idx & 63];
}

// ---------------------------------------------------------------------------
// K5a: s3v partial over 512-row chunk, online softmax. grid (BH, NCH).
// ---------------------------------------------------------------------------
__global__ __launch_bounds__(256) void k_s3v_part(
    const float* __restrict__ qlm, const float* __restrict__ Kt,
    const float* __restrict__ Vt, const float* __restrict__ mask,
    float* __restrict__ Opart, float* __restrict__ mpart, float* __restrict__ spart)
{
    __shared__ float Ql[64][65];
    __shared__ float Ks[64][65];
    __shared__ float Vs[64][64];
    __shared__ float S[64][65];
    __shared__ float rowmax[64], rowsum[64], fac[64], mrow[64];
    const int bh = blockIdx.x, ch = blockIdx.y;
    const int b = bh >> 4;
    const int tid = threadIdx.x;
    const int tx = tid & 15, ty = tid >> 4;
    const int i0 = ty << 2, j0 = tx << 2;
    for (int idx = tid; idx < 4096; idx += 256)
        Ql[idx >> 6][idx & 63] = qlm[(size_t)bh * 4096 + idx];
    if (tid < 64) { rowmax[tid] = -1e30f; rowsum[tid] = 0.f; }
    float acc[4][4] = {};
    const int t0beg = ch * (Ln / NCH), t0end = t0beg + (Ln / NCH);
    for (int t0 = t0beg; t0 < t0end; t0 += 64) {
        __syncthreads();
        for (int idx = tid; idx < 4096; idx += 256) {
            const int r = idx >> 6, c2 = idx & 63;
            Ks[r][c2] = Kt[((size_t)bh * Ln + t0 + r) * HDn + c2];
            Vs[r][c2] = Vt[((size_t)bh * Ln + t0 + r) * HDn + c2];
        }
        if (tid < 64) mrow[tid] = mask[b * Ln + t0 + tid];
        __syncthreads();
        float sacc[4][4] = {};
        for (int k = 0; k < 64; ++k) {
            float a[4], bb4[4];
            #pragma unroll
            for (int i = 0; i < 4; ++i) a[i] = Ql[i0 + i][k];
            #pragma unroll
            for (int j = 0; j < 4; ++j) bb4[j] = Ks[j0 + j][k];
            #pragma unroll
            for (int i = 0; i < 4; ++i)
                #pragma unroll
                for (int j = 0; j < 4; ++j) sacc[i][j] = fmaf(a[i], bb4[j], sacc[i][j]);
        }
        #pragma unroll
        for (int i = 0; i < 4; ++i)
            #pragma unroll
            for (int j = 0; j < 4; ++j)
                S[i0 + i][j0 + j] = sacc[i][j] + (1.f - mrow[j0 + j]) * NEG_BIG;
        __syncthreads();
        if (tid < 64) {
            const int m = tid;
            float mx = -1e30f;
            for (int j = 0; j < 64; ++j) mx = fmaxf(mx, S[m][j]);
            const float nm = fmaxf(rowmax[m], mx);
            const float f = expf(rowmax[m] - nm);
            float ps = 0.f;
            for (int j = 0; j < 64; ++j) {
                const float e = expf(S[m][j] - nm);
                S[m][j] = e;
                ps += e;
            }
            rowsum[m] = rowsum[m] * f + ps;
            rowmax[m] = nm;
            fac[m] = f;
        }
        __syncthreads();
        #pragma unroll
        for (int i = 0; i < 4; ++i) {
            const float f = fac[i0 + i];
            #pragma unroll
            for (int j = 0; j < 4; ++j) acc[i][j] *= f;
        }
        for (int k = 0; k < 64; ++k) {
            float a[4], bb4[4];
            #pragma unroll
            for (int i = 0; i < 4; ++i) a[i] = S[i0 + i][k];
            #pragma unroll
            for (int j = 0; j < 4; ++j) bb4[j] = Vs[k][j0 + j];
            #pragma unroll
            for (int i = 0; i < 4; ++i)
                #pragma unroll
                for (int j = 0; j < 4; ++j) acc[i][j] = fmaf(a[i], bb4[j], acc[i][j]);
        }
    }
    const size_t ob = (size_t)(bh * NCH + ch) * 4096;
    #pragma unroll
    for (int i = 0; i < 4; ++i)
        #pragma unroll
        for (int j = 0; j < 4; ++j)
            Opart[ob + (i0 + i) * 64 + j0 + j] = acc[i][j];
    if (tid < 64) {
        mpart[(bh * NCH + ch) * 64 + tid] = rowmax[tid];
        spart[(bh * NCH + ch) * 64 + tid] = rowsum[tid];
    }
}

// K5b: merge chunks.
__global__ __launch_bounds__(256) void k_s3v_merge(
    const float* __restrict__ Opart, const float* __restrict__ mpart,
    const float* __restrict__ spart, float* __restrict__ s3v)
{
    const int bh = blockIdx.x, tid = threadIdx.x;
    const int r = tid >> 2, c0 = (tid & 3) * 16;
    float e[NCH];
    float M = -1e30f;
    #pragma unroll
    for (int c = 0; c < NCH; ++c) {
        e[c] = mpart[(bh * NCH + c) * 64 + r];
        M = fmaxf(M, e[c]);
    }
    float S = 0.f;
    #pragma unroll
    for (int c = 0; c < NCH; ++c) {
        e[c] = expf(e[c] - M);
        S += spart[(bh * NCH + c) * 64 + r] * e[c];
    }
    const float invS = 1.f / S;
    for (int col = c0; col < c0 + 16; ++col) {
        float o = 0.f;
        #pragma unroll
        for (int c = 0; c < NCH; ++c)
            o += Opart[(size_t)(bh * NCH + c) * 4096 + r * 64 + col] * e[c];
        s3v[(size_t)bh * 4096 + r * 64 + col] = o * invS;
    }
}

// ---------------------------------------------------------------------------
// K6: W = z_star @ s3v (per bh, 64x64).
// ---------------------------------------------------------------------------
__global__ __launch_bounds__(256) void k_zmul(
    const float* __restrict__ Zs, const float* __restrict__ s3v,
    float* __restrict__ Wm)
{
    __shared__ float Ab[64][65];
    __shared__ float Bb[64][64];
    const int bh = blockIdx.x;
    const int tid = threadIdx.x;
    for (int idx = tid; idx < 4096; idx += 256) {
        Ab[idx >> 6][idx & 63] = Zs[(size_t)bh * 4096 + idx];
        Bb[idx >> 6][idx & 63] = s3v[(size_t)bh * 4096 + idx];
    }
    __syncthreads();
    const int tx = tid & 15, ty = tid >> 4;
    const int i0 = ty << 2, j0 = tx << 2;
    float acc[4][4] = {};
    for (int k = 0; k < 64; ++k) {
        float a[4], bb4[4];
        #pragma unroll
        for (int i = 0; i < 4; ++i) a[i] = Ab[i0 + i][k];
        #pragma unroll
        for (int j = 0; j < 4; ++j) bb4[j] = Bb[k][j0 + j];
        #pragma unroll
        for (int i = 0; i < 4; ++i)
            #pragma unroll
            for (int j = 0; j < 4; ++j) acc[i][j] = fmaf(a[i], bb4[j], acc[i][j]);
    }
    #pragma unroll
    for (int i = 0; i < 4; ++i)
        #pragma unroll
        for (int j = 0; j < 4; ++j)
            Wm[(size_t)bh * 4096 + (i0 + i) * 64 + j0 + j] = acc[i][j];
}

// ---------------------------------------------------------------------------
// K7: out_attn = softmax(q @ k_lm^T) @ W -> fp32 attn [B][L][H*HD].
// ---------------------------------------------------------------------------
__global__ __launch_bounds__(256) void k_attn_out(
    const float* __restrict__ Qt, const float* __restrict__ klm,
    const float* __restrict__ Wm, float* __restrict__ attn)
{
    const int lt = blockIdx.x;
    const int bh = blockIdx.y;
    const int b = bh >> 4, h = bh & 15;
    __shared__ float Qs[64][65];
    __shared__ float Ks[64][65];
    __shared__ float Ws[64][64];
    __shared__ float S[64][65];
    __shared__ float rsum[64];
    const int tid = threadIdx.x;
    const int tx = tid & 15, ty = tid >> 4;
    const int i0 = ty << 2, j0 = tx << 2;
    for (int idx = tid; idx < 4096; idx += 256) {
        const int r = idx >> 6, c2 = idx & 63;
        Qs[r][c2] = Qt[((size_t)bh * Ln + lt * 64 + r) * HDn + c2];
        Ks[r][c2] = klm[(size_t)bh * 4096 + idx];
        Ws[r][c2] = Wm[(size_t)bh * 4096 + idx];
    }
    __syncthreads();
    float sacc[4][4] = {};
    for (int k = 0; k < 64; ++k) {
        float a[4], bb4[4];
        #pragma unroll
        for (int i = 0; i < 4; ++i) a[i] = Qs[i0 + i][k];
        #pragma unroll
        for (int j = 0; j < 4; ++j) bb4[j] = Ks[j0 + j][k];
        #pragma unroll
        for (int i = 0; i < 4; ++i)
            #pragma unroll
            for (int j = 0; j < 4; ++j) sacc[i][j] = fmaf(a[i], bb4[j], sacc[i][j]);
    }
    #pragma unroll
    for (int i = 0; i < 4; ++i)
        #pragma unroll
        for (int j = 0; j < 4; ++j) S[i0 + i][j0 + j] = sacc[i][j];
    __syncthreads();
    if (tid < 64) {
        float mx = -1e30f;
        for (int j = 0; j < 64; ++j) mx = fmaxf(mx, S[tid][j]);
        float ps = 0.f;
        for (int j = 0; j < 64; ++j) {
            const float e = expf(S[tid][j] - mx);
            S[tid][j] = e;
            ps += e;
        }
        rsum[tid] = ps;
    }
    __syncthreads();
    float acc[4][4] = {};
    for (int k = 0; k < 64; ++k) {
        float a[4], bb4[4];
        #pragma unroll
        for (int i = 0; i < 4; ++i) a[i] = S[i0 + i][k];
        #pragma unroll
        for (int j = 0; j < 4; ++j) bb4[j] = Ws[k][j0 + j];
        #pragma unroll
        for (int i = 0; i < 4; ++i)
            #pragma unroll
            for (int j = 0; j < 4; ++j) acc[i][j] = fmaf(a[i], bb4[j], acc[i][j]);
    }
    #pragma unroll
    for (int i = 0; i < 4; ++i) {
        const float inv = 1.f / rsum[i0 + i];
        float4 v;
        v.x = acc[i][0] * inv; v.y = acc[i][1] * inv;
        v.z = acc[i][2] * inv; v.w = acc[i][3] * inv;
        const size_t row = (size_t)(b * Ln + lt * 64 + i0 + i);
        *(float4*)&attn[row * Dn + h * 64 + j0] = v;
    }
}

// ---------------------------------------------------------------------------
extern "C" void kernel_launch(void* const* d_in, const int* in_sizes, int n_in,
                              void* d_out, int out_size, void* d_ws, size_t ws_size,
                              hipStream_t stream)
{
    (void)in_sizes; (void)n_in; (void)out_size; (void)ws_size;
    const float* x    = (const float*)d_in[0];
    const float* mask = (const float*)d_in[1];
    const float* wkqv = (const float*)d_in[2];
    const float* wout = (const float*)d_in[3];
    const float* bout = (const float*)d_in[4];
    float* out = (float*)d_out;
    float* ws  = (float*)d_ws;

    float* Kt   = ws + OFF_KT;
    float* Qt   = ws + OFF_QT;
    float* Vt   = ws + OFF_VT;
    float* qlm  = ws + OFF_QLM;
    float* klm  = ws + OFF_KLM;
    float* s2   = ws + OFF_S2;
    float* zst  = ws + OFF_Z;
    float* s3v  = ws + OFF_S3V;
    float* Wm   = ws + OFF_WM;
    int*   gmax = (int*)(ws + OFF_GM);
    float* mpart = ws + OFF_PM;
    float* spart = ws + OFF_PS;
    float* Opart = ws + OFF_PO;                        // alias wh/wl (dead)
    unsigned short* wh  = (unsigned short*)(ws + OFF_WH);
    unsigned short* wl  = (unsigned short*)(ws + OFF_WL);
    unsigned short* woh = (unsigned short*)(ws + OFF_WOH);  // alias Vt (dead)
    unsigned short* wol = (unsigned short*)(ws + OFF_WOL);
    float* attn = ws + OFF_KT;                         // alias Kt (dead)

    hipMemsetAsync(gmax, 0, 2 * sizeof(int), stream);
    k_pack<<<dim3(24, 32), 256, 0, stream>>>(wkqv, wh, wl);
    k_kqv_gemm<<<128 * 24, 256, 0, stream>>>(x, wh, wl, mask, Kt, Qt, Vt);
    k_landmarks<<<BHn * NLn, 64, 0, stream>>>(Kt, Qt, mask, klm, qlm, gmax);
    k_s2<<<BHn, 64, 0, stream>>>(qlm, klm, s2, gmax);
    k_pinv<<<BHn, 256, 0, stream>>>(s2, gmax, zst);
    k_s3v_part<<<dim3(BHn, NCH), 256, 0, stream>>>(qlm, Kt, Vt, mask, Opart, mpart, spart);
    k_pack<<<dim3(8, 32), 256, 0, stream>>>(wout, woh, wol);
    k_s3v_merge<<<BHn, 256, 0, stream>>>(Opart, mpart, spart, s3v);
    k_zmul<<<BHn, 256, 0, stream>>>(zst, s3v, Wm);
    k_attn_out<<<dim3(Ln / 64, BHn), 256, 0, stream>>>(Qt, klm, Wm, attn);
    k_out_gemm<<<128 * 8, 256, 0, stream>>>(attn, woh, wol, bout, out);
}